// Round 6
// baseline (530.031 us; speedup 1.0000x reference)
//
#include <hip/hip_runtime.h>
#include <math.h>

#define N_NODES 30000
#define N_EDGES 240000
#define DMODEL 256
#define NETYPES 8
#define NGRAPHS 64
#define NLAYERS 3

typedef __attribute__((ext_vector_type(8))) short short8;
typedef __attribute__((ext_vector_type(8))) unsigned short ushort8;
typedef __attribute__((ext_vector_type(4))) float f32x4;

// ---- bf16 split helpers (round-to-nearest-even) ----
__device__ __forceinline__ unsigned short f2bf(float f) {
  union { float f; unsigned u; } v; v.f = f;
  unsigned r = v.u + 0x7FFF + ((v.u >> 16) & 1);
  return (unsigned short)(r >> 16);
}
__device__ __forceinline__ float bf2f(unsigned short h) {
  union { unsigned u; float f; } v; v.u = ((unsigned)h) << 16;
  return v.f;
}

__device__ __forceinline__ void async_g2l(const unsigned short* g, unsigned short* l) {
  __builtin_amdgcn_global_load_lds(
      (const __attribute__((address_space(1))) void*)g,
      (__attribute__((address_space(3))) void*)l, 16, 0, 0);
}

// ---------------- CSR build (by destination node) ----------------
__global__ void k_count_deg(const int* __restrict__ dst, int* __restrict__ deg) {
  int e = blockIdx.x * blockDim.x + threadIdx.x;
  if (e < N_EDGES) atomicAdd(&deg[dst[e]], 1);
}

__global__ __launch_bounds__(1024) void k_scan(const int* __restrict__ deg,
                                               int* __restrict__ rowstart,
                                               int* __restrict__ cursor) {
  const int C = 30;
  int tid = threadIdx.x;
  int base = tid * C;
  int vals[C];
  int sum = 0;
#pragma unroll
  for (int j = 0; j < C; ++j) {
    int idx = base + j;
    int v = (idx < N_NODES) ? deg[idx] : 0;
    vals[j] = sum;
    sum += v;
  }
  int lane = tid & 63, wv = tid >> 6;
  int s = sum;
#pragma unroll
  for (int off = 1; off < 64; off <<= 1) {
    int t2 = __shfl_up(s, off);
    if (lane >= off) s += t2;
  }
  __shared__ int wsum[16];
  if (lane == 63) wsum[wv] = s;
  __syncthreads();
  if (tid == 0) {
    int a = 0;
#pragma unroll
    for (int i = 0; i < 16; ++i) { int t2 = wsum[i]; wsum[i] = a; a += t2; }
    rowstart[N_NODES] = a;
  }
  __syncthreads();
  int texcl = wsum[wv] + (s - sum);
#pragma unroll
  for (int j = 0; j < C; ++j) {
    int idx = base + j;
    if (idx < N_NODES) {
      int p = texcl + vals[j];
      rowstart[idx] = p;
      cursor[idx]   = p;
    }
  }
}

__global__ void k_scatter(const int* __restrict__ src, const int* __restrict__ dst,
                          const int* __restrict__ etype, int* __restrict__ cursor,
                          int* __restrict__ packed) {
  int e = blockIdx.x * blockDim.x + threadIdx.x;
  if (e < N_EDGES) {
    int p = atomicAdd(&cursor[dst[e]], 1);
    packed[p] = src[e] * NETYPES + etype[e];
  }
}

// ---------------- weight transpose (coalesced, LDS tile), bf16 hi only ----------
__global__ __launch_bounds__(256) void k_cvt_w(
    const float* __restrict__ Wq, const float* __restrict__ Wk, const float* __restrict__ Wv,
    unsigned short* __restrict__ wthi) {
  __shared__ float tile[32][33];
  int k0 = blockIdx.x * 32;
  int n0g = blockIdx.y * 32;
  int l = blockIdx.z;
  int which = n0g >> 8;
  int col0 = n0g & 255;
  const float* W = (which == 0) ? Wq : ((which == 1) ? Wk : Wv);
  int c = threadIdx.x & 31, r = threadIdx.x >> 5;
#pragma unroll
  for (int rr = 0; rr < 4; ++rr) {
    int kk = r + rr * 8;
    tile[kk][c] = W[(size_t)l * 65536 + (size_t)(k0 + kk) * 256 + col0 + c];
  }
  __syncthreads();
  int kk = threadIdx.x & 31, nn0 = threadIdx.x >> 5;
#pragma unroll
  for (int rr = 0; rr < 4; ++rr) {
    int nn = nn0 + rr * 8;
    wthi[((size_t)l * 768 + n0g + nn) * 256 + k0 + kk] = f2bf(tile[kk][nn]);
  }
}

__global__ void k_cvt_b(const float* __restrict__ bq, const float* __restrict__ bk,
                        const float* __restrict__ bv, float* __restrict__ bcat) {
  int idx = blockIdx.x * 256 + threadIdx.x;
  if (idx >= NLAYERS * 768) return;
  int n = idx % 768, l = idx / 768;
  int which = n >> 8, col = n & 255;
  const float* b = (which == 0) ? bq : ((which == 1) ? bk : bv);
  bcat[idx] = b[l * 256 + col];
}

__global__ void k_cvt_x(const float* __restrict__ x, unsigned short* __restrict__ xhi,
                        unsigned short* __restrict__ xlo) {
  int i = blockIdx.x * 256 + threadIdx.x;
  if (i < N_NODES * 256) {
    float v = x[i];
    unsigned short h = f2bf(v);
    xhi[i] = h;
    xlo[i] = f2bf(v - bf2f(h));
  }
}

// ---------------- split-bf16 MFMA GEMM, 2-term, XCD-swizzled grid ----------
// bx = x + 8*(rg*6 + c); r = rg*8 + x  =>  all 6 col-blocks of row r share
// XCD x (bx%8==x) and are consecutive in that XCD's dispatch order -> A-tile
// stays in the XCD's 4MB L2.  grid = 1440 (tail blocks idle).
__global__ __launch_bounds__(256) void k_gemm_mfma(
    const unsigned short* __restrict__ Ahi, const unsigned short* __restrict__ Alo,
    const unsigned short* __restrict__ Bhi,
    const float* __restrict__ bcat, float* __restrict__ qbuf,
    unsigned short* __restrict__ kvb) {
  __shared__ unsigned short smem[3 * 4096];
  unsigned short* sAhi = smem;
  unsigned short* sAlo = smem + 4096;
  unsigned short* sBhi = smem + 8192;

  int x = blockIdx.x & 7, j0 = blockIdx.x >> 3;
  int rg = j0 / 6, c0 = j0 % 6;
  int r0 = rg * 8 + x;
  if (r0 >= 235) return;
  int row0 = r0 * 128;
  int n0 = c0 * 128;

  int tid = threadIdx.x;
  int lane = tid & 63, wave = tid >> 6;
  int wm = (wave >> 1) * 64, wn = (wave & 1) * 64;
  int quad = lane >> 4, l16 = lane & 15;
  int chunk = lane & 3;
  int srow = wave * 32 + (lane >> 2);

  f32x4 acc[4][4];
#pragma unroll
  for (int i = 0; i < 4; ++i)
#pragma unroll
    for (int j = 0; j < 4; ++j) acc[i][j] = (f32x4)(0.f);

  for (int k0 = 0; k0 < 256; k0 += 32) {
#pragma unroll
    for (int j = 0; j < 2; ++j) {
      int r = srow + j * 16;
      int ldsoff = wave * 1024 + j * 512;
      int garA = row0 + r; if (garA >= N_NODES) garA = N_NODES - 1;
      size_t aoff = (size_t)garA * 256 + k0 + chunk * 8;
      async_g2l(Ahi + aoff, sAhi + ldsoff);
      async_g2l(Alo + aoff, sAlo + ldsoff);
      size_t boff = (size_t)(n0 + r) * 256 + k0 + chunk * 8;
      async_g2l(Bhi + boff, sBhi + ldsoff);
    }
    __syncthreads();
    short8 ah[4], al[4], bh[4];
#pragma unroll
    for (int i = 0; i < 4; ++i) {
      int off = (wm + i * 16 + l16) * 32 + quad * 8;
      ah[i] = *(const short8*)(sAhi + off);
      al[i] = *(const short8*)(sAlo + off);
    }
#pragma unroll
    for (int j = 0; j < 4; ++j) {
      int off = (wn + j * 16 + l16) * 32 + quad * 8;
      bh[j] = *(const short8*)(sBhi + off);
    }
#pragma unroll
    for (int i = 0; i < 4; ++i)
#pragma unroll
      for (int j = 0; j < 4; ++j) {
        acc[i][j] = __builtin_amdgcn_mfma_f32_16x16x32_bf16(ah[i], bh[j], acc[i][j], 0, 0, 0);
        acc[i][j] = __builtin_amdgcn_mfma_f32_16x16x32_bf16(al[i], bh[j], acc[i][j], 0, 0, 0);
      }
    __syncthreads();
  }

  float bj[4];
#pragma unroll
  for (int j = 0; j < 4; ++j) bj[j] = bcat[n0 + wn + j * 16 + l16];
#pragma unroll
  for (int i = 0; i < 4; ++i) {
    int rowb = row0 + wm + i * 16 + quad * 4;
#pragma unroll
    for (int r = 0; r < 4; ++r) {
      int grow = rowb + r;
      if (grow < N_NODES) {
#pragma unroll
        for (int j = 0; j < 4; ++j) {
          int col = n0 + wn + l16 + j * 16;
          float val = acc[i][j][r] + bj[j];
          if (col < 256) {
            qbuf[(size_t)grow * 256 + col] = val;
          } else if (col < 512) {
            kvb[(size_t)grow * 512 + (col - 256) * 2] = f2bf(val);       // k
          } else {
            kvb[(size_t)grow * 512 + (col - 512) * 2 + 1] = f2bf(val);   // v
          }
        }
      }
    }
  }
}

// ---------------- per-dst-node edge attention ----------
// score = (k.q + e.q)*s via per-node eq[head][type] table; agg = sum(a*v) +
// sum_t w_t*e_t with w_t lane-distributed per head. One dwordx4 kv load/edge.
#define EDGE_BODY(PK, R8, LS, AX, AY, AZ, AW, WACC)                          \
  {                                                                          \
    float kx = bf2f(R8[0]), vx = bf2f(R8[1]);                                \
    float ky = bf2f(R8[2]), vy = bf2f(R8[3]);                                \
    float kz = bf2f(R8[4]), vz = bf2f(R8[5]);                                \
    float kw = bf2f(R8[6]), vw = bf2f(R8[7]);                                \
    float p = kx * q4.x + ky * q4.y + kz * q4.z + kw * q4.w;                 \
    p += __shfl_xor(p, 1); p += __shfl_xor(p, 2);                            \
    p += __shfl_xor(p, 4); p += __shfl_xor(p, 8);                            \
    int et = (PK) & 7;                                                       \
    float sc = fmaf(p, 0.125f, eqtab[eqbase + et]);                          \
    float e1 = __expf(sc);                                                   \
    LS += e1;                                                                \
    WACC += ((lane & 7) == et) ? e1 : 0.f;                                   \
    AX = fmaf(e1, vx, AX); AY = fmaf(e1, vy, AY);                            \
    AZ = fmaf(e1, vz, AZ); AW = fmaf(e1, vw, AW);                            \
  }

__global__ __launch_bounds__(256) void k_attn(
    const float* __restrict__ qbuf, const unsigned short* __restrict__ kvb,
    const int* __restrict__ rowstart, const int* __restrict__ packed,
    const float* __restrict__ Eemb_l,
    unsigned short* __restrict__ xhi, unsigned short* __restrict__ xlo) {
  __shared__ float ete_s[NETYPES * 256];
  __shared__ float eqtab[4 * 4 * 8];   // [slot][head][type], eq pre-scaled
  int t = threadIdx.x;
#pragma unroll
  for (int i = 0; i < NETYPES; ++i) ete_s[i * 256 + t] = Eemb_l[i * 256 + t];
  __syncthreads();
  int lane = t & 63, slot = t >> 6;
  int n = blockIdx.x * 4 + slot;
  float4 q4 = ((const float4*)(qbuf + (size_t)n * 256))[lane];
  int head = lane >> 4;
  // per-node eq table: eq[head][type] = (e_t . q_head) * scale
#pragma unroll
  for (int ty = 0; ty < NETYPES; ++ty) {
    float4 e4 = ((const float4*)(ete_s + ty * 256))[lane];
    float d = e4.x * q4.x + e4.y * q4.y + e4.z * q4.z + e4.w * q4.w;
    d += __shfl_xor(d, 1); d += __shfl_xor(d, 2);
    d += __shfl_xor(d, 4); d += __shfl_xor(d, 8);
    if ((lane & 15) == ty) eqtab[slot * 32 + head * 8 + ty] = d * 0.125f;
  }
  __syncthreads();
  int eqbase = slot * 32 + head * 8;
  int rs = rowstart[n], re = rowstart[n + 1];
  float l1 = 0.f, ax1 = 0.f, ay1 = 0.f, az1 = 0.f, aw1 = 0.f, w1 = 0.f;
  float l2 = 0.f, ax2 = 0.f, ay2 = 0.f, az2 = 0.f, aw2 = 0.f, w2 = 0.f;
  int i = rs;
  for (; i + 4 <= re; i += 4) {
    int p0 = packed[i], p1 = packed[i + 1], p2 = packed[i + 2], p3 = packed[i + 3];
    ushort8 r0 = *(const ushort8*)(kvb + (size_t)(p0 >> 3) * 512 + lane * 8);
    ushort8 r1 = *(const ushort8*)(kvb + (size_t)(p1 >> 3) * 512 + lane * 8);
    ushort8 r2 = *(const ushort8*)(kvb + (size_t)(p2 >> 3) * 512 + lane * 8);
    ushort8 r3 = *(const ushort8*)(kvb + (size_t)(p3 >> 3) * 512 + lane * 8);
    EDGE_BODY(p0, r0, l1, ax1, ay1, az1, aw1, w1);
    EDGE_BODY(p1, r1, l2, ax2, ay2, az2, aw2, w2);
    EDGE_BODY(p2, r2, l1, ax1, ay1, az1, aw1, w1);
    EDGE_BODY(p3, r3, l2, ax2, ay2, az2, aw2, w2);
  }
  for (; i < re; ++i) {
    int p0 = packed[i];
    ushort8 r0 = *(const ushort8*)(kvb + (size_t)(p0 >> 3) * 512 + lane * 8);
    EDGE_BODY(p0, r0, l1, ax1, ay1, az1, aw1, w1);
  }
  float l = l1 + l2;
  float ax = ax1 + ax2, ay = ay1 + ay2, az = az1 + az2, aw = aw1 + aw2;
  float w = w1 + w2;
  // add sum_t w_t * e_t; w_t lives in this lane's own head group:
  // lanes head*16+0..7 (and 8..15 duplicate) hold head's per-type sums.
#pragma unroll
  for (int ty = 0; ty < NETYPES; ++ty) {
    float wt = __shfl(w, (lane & 48) + ty);
    const float* ep = ete_s + ty * 256 + lane * 4;
    ax = fmaf(wt, ep[0], ax); ay = fmaf(wt, ep[1], ay);
    az = fmaf(wt, ep[2], az); aw = fmaf(wt, ep[3], aw);
  }
  float inv = 1.f / (l + 1e-16f);
  float4 o;
  o.x = ax * inv; o.y = ay * inv; o.z = az * inv; o.w = aw * inv;
  o.x = o.x > 0.f ? o.x : expm1f(o.x);
  o.y = o.y > 0.f ? o.y : expm1f(o.y);
  o.z = o.z > 0.f ? o.z : expm1f(o.z);
  o.w = o.w > 0.f ? o.w : expm1f(o.w);
  unsigned short h0 = f2bf(o.x), h1 = f2bf(o.y), h2 = f2bf(o.z), h3 = f2bf(o.w);
  ushort4 hv, lv;
  hv.x = h0; hv.y = h1; hv.z = h2; hv.w = h3;
  lv.x = f2bf(o.x - bf2f(h0)); lv.y = f2bf(o.y - bf2f(h1));
  lv.z = f2bf(o.z - bf2f(h2)); lv.w = f2bf(o.w - bf2f(h3));
  size_t base_o = (size_t)n * 256 + lane * 4;
  *(ushort4*)(xhi + base_o) = hv;
  *(ushort4*)(xlo + base_o) = lv;
}

// ---------------- parallel mean pool, stage 1 ----------------
__global__ __launch_bounds__(256) void k_pool_partial(
    const unsigned short* __restrict__ xhi, const unsigned short* __restrict__ xlo,
    const int* __restrict__ batch, float* __restrict__ gacc) {
  int t = threadIdx.x;
  int base = blockIdx.x * 128;
  int end = base + 128; if (end > N_NODES) end = N_NODES;
  __shared__ int bsh[128];
  if (t < 128 && base + t < N_NODES) bsh[t] = batch[base + t];
  __syncthreads();
  float acc = 0.f;
  int cur = bsh[0];
  for (int n = base; n < end; ++n) {
    int g = bsh[n - base];
    if (g != cur) {
      atomicAdd(&gacc[cur * 256 + t], acc);
      acc = 0.f; cur = g;
    }
    size_t idx = (size_t)n * 256 + t;
    acc += bf2f(xhi[idx]) + bf2f(xlo[idx]);
  }
  atomicAdd(&gacc[cur * 256 + t], acc);
}

// ---------------- GRU (h0=0) + FC ----------------
__device__ inline int lower_bound_dev(const int* a, int n, int val) {
  int lo = 0, hi = n;
  while (lo < hi) {
    int mid = (lo + hi) >> 1;
    if (a[mid] < val) lo = mid + 1; else hi = mid;
  }
  return lo;
}

__global__ __launch_bounds__(256) void k_gru_fc(
    const float* __restrict__ gacc, const int* __restrict__ batch,
    const float* __restrict__ W_ih, const float* __restrict__ b_ih,
    const float* __restrict__ b_hh, const float* __restrict__ W_fc,
    const float* __restrict__ b_fc, float* __restrict__ out) {
  __shared__ float gv[256];
  __shared__ float gates[192];
  __shared__ float h[64];
  int gr = blockIdx.x, t = threadIdx.x;
  int s0 = lower_bound_dev(batch, N_NODES, gr);
  int e0 = lower_bound_dev(batch, N_NODES, gr + 1);
  float c = (e0 > s0) ? (float)(e0 - s0) : 1.f;
  gv[t] = gacc[gr * 256 + t] / c;
  __syncthreads();
  if (t < 192) {
    const float* wr = W_ih + t * 256;
    float s = b_ih[t];
    for (int k = 0; k < 256; ++k) s = fmaf(gv[k], wr[k], s);
    gates[t] = s;
  }
  __syncthreads();
  if (t < 64) {
    float r  = 1.f / (1.f + expf(-(gates[t] + b_hh[t])));
    float z  = 1.f / (1.f + expf(-(gates[64 + t] + b_hh[64 + t])));
    float nn = tanhf(gates[128 + t] + r * b_hh[128 + t]);
    h[t] = (1.f - z) * nn;
  }
  __syncthreads();
  if (t < 2) {
    const float* wr = W_fc + t * 64;
    float s = b_fc[t];
    for (int k = 0; k < 64; ++k) s = fmaf(h[k], wr[k], s);
    out[gr * 2 + t] = s;
  }
}

extern "C" void kernel_launch(void* const* d_in, const int* in_sizes, int n_in,
                              void* d_out, int out_size, void* d_ws, size_t ws_size,
                              hipStream_t stream) {
  const float* x     = (const float*)d_in[0];
  const int* edge_index = (const int*)d_in[1];
  const int* batch   = (const int*)d_in[2];
  const int* etype   = (const int*)d_in[3];
  const float* Wq    = (const float*)d_in[4];
  const float* bq    = (const float*)d_in[5];
  const float* Wk    = (const float*)d_in[6];
  const float* bk    = (const float*)d_in[7];
  const float* Wv    = (const float*)d_in[8];
  const float* bv    = (const float*)d_in[9];
  const float* Eemb  = (const float*)d_in[10];
  const float* W_ih  = (const float*)d_in[11];
  const float* b_ih  = (const float*)d_in[12];
  const float* b_hh  = (const float*)d_in[14];
  const float* W_fc  = (const float*)d_in[15];
  const float* b_fc  = (const float*)d_in[16];
  float* out = (float*)d_out;

  const int* src = edge_index;
  const int* dst = edge_index + N_EDGES;

  float* qbuf  = (float*)d_ws;                             // N*256 f32
  float* gacc  = qbuf + (size_t)N_NODES * 256;             // 64*256
  float* bcat  = gacc + NGRAPHS * 256;                     // 3*768
  unsigned short* kvb  = (unsigned short*)(bcat + NLAYERS * 768);  // N*512 bf16 interleaved
  unsigned short* xhi  = kvb + (size_t)N_NODES * 512;      // N*256
  unsigned short* xlo  = xhi + (size_t)N_NODES * 256;
  unsigned short* wthi = xlo + (size_t)N_NODES * 256;      // 3*768*256
  int* deg      = (int*)(wthi + (size_t)NLAYERS * 768 * 256);
  int* rowstart = deg + N_NODES;
  int* cursor   = rowstart + N_NODES + 1;
  int* packed   = cursor + N_NODES;

  hipMemsetAsync(deg, 0, N_NODES * sizeof(int), stream);
  hipMemsetAsync(gacc, 0, NGRAPHS * 256 * sizeof(float), stream);
  k_count_deg<<<(N_EDGES + 255) / 256, 256, 0, stream>>>(dst, deg);
  k_scan<<<1, 1024, 0, stream>>>(deg, rowstart, cursor);
  k_scatter<<<(N_EDGES + 255) / 256, 256, 0, stream>>>(src, dst, etype, cursor, packed);

  k_cvt_w<<<dim3(8, 24, 3), 256, 0, stream>>>(Wq, Wk, Wv, wthi);
  k_cvt_b<<<(NLAYERS * 768 + 255) / 256, 256, 0, stream>>>(bq, bk, bv, bcat);
  k_cvt_x<<<(N_NODES * 256 + 255) / 256, 256, 0, stream>>>(x, xhi, xlo);

  for (int l = 0; l < NLAYERS; ++l) {
    k_gemm_mfma<<<1440, 256, 0, stream>>>(
        xhi, xlo, wthi + (size_t)l * 768 * 256,
        bcat + l * 768, qbuf, kvb);
    k_attn<<<N_NODES / 4, 256, 0, stream>>>(qbuf, kvb, rowstart, packed,
                                            Eemb + (size_t)l * NETYPES * 256, xhi, xlo);
  }
  k_pool_partial<<<(N_NODES + 127) / 128, 256, 0, stream>>>(xhi, xlo, batch, gacc);
  k_gru_fc<<<NGRAPHS, 256, 0, stream>>>(gacc, batch, W_ih, b_ih, b_hh, W_fc, b_fc, out);
}